// Round 6
// baseline (593.849 us; speedup 1.0000x reference)
//
#include <hip/hip_runtime.h>

#define HWPX 9216   // 96*96
#define NCH  128

typedef float  f32x4  __attribute__((ext_vector_type(4)));
typedef __bf16 bf16x8 __attribute__((ext_vector_type(8)));
typedef __bf16 bf16x4 __attribute__((ext_vector_type(4)));

#define SWZ16(row) ((((row) & 7) ^ (((row) >> 3) << 1)) << 4)

// DPP reduction over a 16-lane row: xor1, xor2 (quad_perm), then ror4, ror8.
#define DPP_RED(v, OP)                                                         \
  do {                                                                         \
    v = OP(v, __int_as_float(__builtin_amdgcn_update_dpp(                      \
               0, __float_as_int(v), 0xB1, 0xF, 0xF, true)));                  \
    v = OP(v, __int_as_float(__builtin_amdgcn_update_dpp(                      \
               0, __float_as_int(v), 0x4E, 0xF, 0xF, true)));                  \
    v = OP(v, __int_as_float(__builtin_amdgcn_update_dpp(                      \
               0, __float_as_int(v), 0x124, 0xF, 0xF, true)));                 \
    v = OP(v, __int_as_float(__builtin_amdgcn_update_dpp(                      \
               0, __float_as_int(v), 0x128, 0xF, 0xF, true)));                 \
  } while (0)
__device__ __forceinline__ float op_max(float a, float b) { return fmaxf(a, b); }
__device__ __forceinline__ float op_add(float a, float b) { return a + b; }

// ---------------------------------------------------------------------------
// prep: Wb = (j,o,c) bf16; wck = (tap,o,c) bf16; Xb = x^T (px,c) bf16.
// ---------------------------------------------------------------------------
__global__ __launch_bounds__(256) void prep_kernel(
    const float* __restrict__ w1, const float* __restrict__ w2,
    const float* __restrict__ w3, const float* __restrict__ wc,
    const float* __restrict__ x,
    __bf16* __restrict__ Wb, __bf16* __restrict__ wck,
    __bf16* __restrict__ Xb) {
  int tid = blockIdx.x * 256 + threadIdx.x;
  int nt  = gridDim.x * 256;
  for (int idx = tid; idx < 3 * 16384; idx += nt) {
    int j = idx >> 14;
    const float* w = (j == 0) ? w1 : (j == 1 ? w2 : w3);
    Wb[idx] = (__bf16)w[idx & 16383];
  }
  for (int idx = tid; idx < 147456; idx += nt) {   // wc is (O, C, 3, 3)
    int k = idx % 9;
    int rest = idx / 9;            // o*128 + c
    int c = rest & 127, o = rest >> 7;
    wck[(k * 128 + o) * 128 + c] = (__bf16)wc[idx];
  }
  for (int idx = tid; idx < 128 * HWPX; idx += nt) {  // x (c,px) -> Xb (px,c)
    int c = idx / HWPX, p = idx - c * HWPX;
    Xb[p * 128 + c] = (__bf16)x[idx];
  }
}

// ---------------------------------------------------------------------------
// conv1x1 x3 + bias + PReLU as MFMA GEMM.  grid (144, 6).
// ---------------------------------------------------------------------------
__global__ __launch_bounds__(256) void conv1x1_qkv(
    const __bf16* __restrict__ Xb, const __bf16* __restrict__ Wb,
    const float* __restrict__ b1, const float* __restrict__ b2,
    const float* __restrict__ b3, const float* __restrict__ a1,
    const float* __restrict__ a2, const float* __restrict__ a3,
    __bf16* __restrict__ Q, __bf16* __restrict__ K, __bf16* __restrict__ Vt) {
  const int tid = threadIdx.x, lane = tid & 63, w = tid >> 6;
  const int l16 = lane & 15, hi = lane >> 4;
  const int p0 = blockIdx.x * 64;
  const int z  = blockIdx.y;

  bf16x8 af[4][4];
#pragma unroll
  for (int pxt = 0; pxt < 4; ++pxt)
#pragma unroll
    for (int kc = 0; kc < 4; ++kc)
      af[pxt][kc] = *(const bf16x8*)&Xb[(p0 + pxt * 16 + l16) * 128 + kc * 32 + hi * 8];

  const int obase = w * 96 + z * 16;
  const int j = obase >> 7;
  const int oo = (obase & 127) + l16;
  bf16x8 bfg[4];
#pragma unroll
  for (int kc = 0; kc < 4; ++kc)
    bfg[kc] = *(const bf16x8*)&Wb[(obase + l16) * 128 + kc * 32 + hi * 8];
  f32x4 acc[4];
#pragma unroll
  for (int pxt = 0; pxt < 4; ++pxt) acc[pxt] = (f32x4){0.f, 0.f, 0.f, 0.f};
#pragma unroll
  for (int kc = 0; kc < 4; ++kc)
#pragma unroll
    for (int pxt = 0; pxt < 4; ++pxt)
      acc[pxt] = __builtin_amdgcn_mfma_f32_16x16x32_bf16(af[pxt][kc], bfg[kc], acc[pxt], 0, 0, 0);

  const float* bp = (j == 0) ? b1 : (j == 1 ? b2 : b3);
  const float bias = bp[oo];
  const float* ap = (j == 0) ? a1 : (j == 1 ? a2 : a3);
  const float sl = ap[0];
#pragma unroll
  for (int pxt = 0; pxt < 4; ++pxt)
#pragma unroll
    for (int r = 0; r < 4; ++r) {
      float v = acc[pxt][r] + bias;
      v = (v >= 0.f) ? v : sl * v;
      int px = p0 + pxt * 16 + hi * 4 + r;
      if (j == 0)      Q[px * 128 + oo] = (__bf16)v;
      else if (j == 1) K[px * 128 + oo] = (__bf16)v;
      else             Vt[oo * HWPX + px] = (__bf16)v;
    }
}

// ---------------------------------------------------------------------------
// Flash attention, split-K.  4 waves x 32 q = 128 q/block, grid (72, ksplit).
// LDS 64KB: K double-buffer 2x16KB @0/@16384, V single 16KB @32768,
// P per-wave [32][128B] @49152 + w*4096.  2 blocks/CU.
// K prefetched one tile ahead (gload_lds, pre-swizzled global src); V issued
// post-barrier and overlaps the next QK+softmax.  Counted vmcnt, raw barriers.
// ---------------------------------------------------------------------------
__global__ __launch_bounds__(256) void flash_attn(
    const __bf16* __restrict__ Q, const __bf16* __restrict__ Kb,
    const __bf16* __restrict__ Vt, float* __restrict__ Opart,
    float* __restrict__ mOut, float* __restrict__ lOut, int nt) {
  __shared__ __align__(16) unsigned char smem[65536];
  const int tid  = threadIdx.x;
  const int lane = tid & 63;
  const int w    = tid >> 6;      // 0..3
  const int l16  = lane & 15;
  const int hi   = lane >> 4;
  const int ord  = blockIdx.y * 72 + blockIdx.x;
  const int nsp  = gridDim.y;
  const int split = ord % nsp;
  const int qb   = (ord / nsp) * 128;
  const int kt0  = split * nt;

  // staging address precompute (each wave: 4 K segs + 4 V segs of 1KB)
  int koff[4], voff_ch;
#pragma unroll
  for (int j = 0; j < 4; ++j) {
    int krow = w * 16 + j * 4 + hi;
    koff[j] = krow * 128 + (((lane & 15) ^ (krow & 7)) * 8);
  }
  voff_ch = (((lane & 7) ^ ((lane >> 3) & 7)) * 8);

#define STAGE_K(BUF, KT) do {                                                  \
  _Pragma("unroll")                                                            \
  for (int j = 0; j < 4; ++j)                                                  \
    __builtin_amdgcn_global_load_lds(                                          \
        (const __attribute__((address_space(1))) unsigned int*)                \
            (Kb + (size_t)(KT) * 8192 + koff[j]),                              \
        (__attribute__((address_space(3))) unsigned int*)                      \
            (smem + (BUF) * 16384 + (w * 4 + j) * 1024),                       \
        16, 0, 0);                                                             \
  } while (0)

#define STAGE_V(KT) do {                                                       \
  _Pragma("unroll")                                                            \
  for (int j = 0; j < 4; ++j) {                                                \
    int vd = w * 32 + j * 8 + (lane >> 3);                                     \
    __builtin_amdgcn_global_load_lds(                                          \
        (const __attribute__((address_space(1))) unsigned int*)                \
            (Vt + (size_t)vd * HWPX + (size_t)(KT) * 64 + voff_ch),            \
        (__attribute__((address_space(3))) unsigned int*)                      \
            (smem + 32768 + (w * 4 + j) * 1024),                               \
        16, 0, 0);                                                             \
  } } while (0)

  // Q fragments: 32 q per wave (two 16-row groups)
  bf16x8 qf[2][4];
#pragma unroll
  for (int g2 = 0; g2 < 2; ++g2) {
    const int qrow = qb + w * 32 + g2 * 16 + l16;
#pragma unroll
    for (int dc = 0; dc < 4; ++dc)
      qf[g2][dc] = *(const bf16x8*)&Q[qrow * 128 + dc * 32 + hi * 8];
  }

  f32x4 oacc[2][8];
#pragma unroll
  for (int g2 = 0; g2 < 2; ++g2)
#pragma unroll
    for (int dc = 0; dc < 8; ++dc) oacc[g2][dc] = (f32x4){0.f, 0.f, 0.f, 0.f};
  float m[2][4], l[2][4];
#pragma unroll
  for (int g2 = 0; g2 < 2; ++g2)
#pragma unroll
    for (int r = 0; r < 4; ++r) { m[g2][r] = -INFINITY; l[g2][r] = 0.f; }

  const unsigned pbase = 49152 + w * 4096;
  f32x4 s[2][4];
  bf16x8 pa[2][2];

#define COMPUTE_QK(CUR)                                                        \
  do {                                                                         \
    const unsigned kb0 = (CUR) * 16384;                                        \
    __builtin_amdgcn_s_setprio(1);                                             \
    _Pragma("unroll")                                                          \
    for (int g = 0; g < 4; ++g) {                                              \
      int row = g * 16 + l16;                                                  \
      bf16x8 kf[4];                                                            \
      _Pragma("unroll")                                                        \
      for (int dc = 0; dc < 4; ++dc)                                           \
        kf[dc] = *(const bf16x8*)&smem[kb0 + row * 256 +                       \
                     ((dc * 64 + hi * 16) ^ ((row & 7) << 4))];                \
      _Pragma("unroll")                                                        \
      for (int dc = 0; dc < 4; ++dc) {                                         \
        s[0][g] = __builtin_amdgcn_mfma_f32_16x16x32_bf16(qf[0][dc], kf[dc],   \
                                                          s[0][g], 0, 0, 0);   \
        s[1][g] = __builtin_amdgcn_mfma_f32_16x16x32_bf16(qf[1][dc], kf[dc],   \
                                                          s[1][g], 0, 0, 0);   \
      }                                                                        \
    }                                                                          \
    __builtin_amdgcn_s_setprio(0);                                             \
  } while (0)

#define SOFTMAX_P()                                                            \
  do {                                                                         \
    float mx[2][4];                                                            \
    bool need = false;                                                         \
    _Pragma("unroll")                                                          \
    for (int g2 = 0; g2 < 2; ++g2)                                             \
      _Pragma("unroll")                                                        \
      for (int r = 0; r < 4; ++r) {                                            \
        float v = fmaxf(fmaxf(s[g2][0][r], s[g2][1][r]),                       \
                        fmaxf(s[g2][2][r], s[g2][3][r]));                      \
        DPP_RED(v, op_max);                                                    \
        mx[g2][r] = v;                                                         \
        need = need || (v > m[g2][r] + 8.f);                                   \
      }                                                                        \
    if (__any(need)) {                                                         \
      _Pragma("unroll")                                                        \
      for (int g2 = 0; g2 < 2; ++g2)                                           \
        _Pragma("unroll")                                                      \
        for (int r = 0; r < 4; ++r) {                                          \
          float mn = fmaxf(m[g2][r], mx[g2][r]);                               \
          float alpha = __expf(m[g2][r] - mn);                                 \
          m[g2][r] = mn;                                                       \
          l[g2][r] *= alpha;                                                   \
          _Pragma("unroll")                                                    \
          for (int dc = 0; dc < 8; ++dc) oacc[g2][dc][r] *= alpha;             \
        }                                                                      \
    }                                                                          \
    _Pragma("unroll")                                                          \
    for (int g2 = 0; g2 < 2; ++g2) {                                           \
      float rs[4];                                                             \
      _Pragma("unroll")                                                        \
      for (int r = 0; r < 4; ++r) rs[r] = 0.f;                                 \
      _Pragma("unroll")                                                        \
      for (int g = 0; g < 4; ++g)                                              \
        _Pragma("unroll")                                                      \
        for (int r = 0; r < 4; ++r) {                                          \
          float p = __expf(s[g2][g][r] - m[g2][r]);                            \
          s[g2][g][r] = p;                                                     \
          rs[r] += p;                                                          \
        }                                                                      \
      _Pragma("unroll")                                                        \
      for (int r = 0; r < 4; ++r) {                                            \
        DPP_RED(rs[r], op_add);                                                \
        l[g2][r] += rs[r];                                                     \
      }                                                                        \
      _Pragma("unroll")                                                        \
      for (int g = 0; g < 4; ++g)                                              \
        _Pragma("unroll")                                                      \
        for (int r = 0; r < 4; ++r) {                                          \
          int row = g2 * 16 + hi * 4 + r;                                      \
          *(__bf16*)&smem[pbase + row * 128 +                                  \
                          ((g * 32 + l16 * 2) ^ SWZ16(row))] =                 \
              (__bf16)s[g2][g][r];                                             \
        }                                                                      \
    }                                                                          \
    _Pragma("unroll")                                                          \
    for (int g2 = 0; g2 < 2; ++g2) {                                           \
      int row = g2 * 16 + l16;                                                 \
      _Pragma("unroll")                                                        \
      for (int kc = 0; kc < 2; ++kc)                                           \
        pa[g2][kc] = *(const bf16x8*)&smem[pbase + row * 128 +                 \
                         ((kc * 64 + hi * 16) ^ SWZ16(row))];                  \
    }                                                                          \
  } while (0)

#define COMPUTE_PV()                                                           \
  do {                                                                         \
    __builtin_amdgcn_s_setprio(1);                                             \
    _Pragma("unroll")                                                          \
    for (int dc = 0; dc < 8; ++dc) {                                           \
      int row = dc * 16 + l16;                                                 \
      _Pragma("unroll")                                                        \
      for (int kc = 0; kc < 2; ++kc) {                                         \
        bf16x8 vf = *(const bf16x8*)&smem[32768 + row * 128 +                  \
                        ((kc * 64 + hi * 16) ^ ((row & 7) << 4))];             \
        oacc[0][dc] = __builtin_amdgcn_mfma_f32_16x16x32_bf16(                 \
            pa[0][kc], vf, oacc[0][dc], 0, 0, 0);                              \
        oacc[1][dc] = __builtin_amdgcn_mfma_f32_16x16x32_bf16(                 \
            pa[1][kc], vf, oacc[1][dc], 0, 0, 0);                              \
      }                                                                        \
    }                                                                          \
    __builtin_amdgcn_s_setprio(0);                                             \
  } while (0)

  // prologue
  STAGE_K(0, kt0);
  STAGE_V(kt0);
  asm volatile("s_waitcnt vmcnt(0)" ::: "memory");
  __builtin_amdgcn_s_barrier();

  int cur = 0;
  for (int it = 0; it < nt - 1; ++it) {
    STAGE_K(cur ^ 1, kt0 + it + 1);
#pragma unroll
    for (int g2 = 0; g2 < 2; ++g2)
#pragma unroll
      for (int g = 0; g < 4; ++g) s[g2][g] = (f32x4){0.f, 0.f, 0.f, 0.f};
    COMPUTE_QK(cur);
    SOFTMAX_P();
    asm volatile("s_waitcnt vmcnt(4)" ::: "memory");   // own V(t) landed
    __builtin_amdgcn_s_barrier();                      // all waves' V landed
    COMPUTE_PV();
    asm volatile("s_waitcnt vmcnt(0)" ::: "memory");   // own K(t+1) landed
    __builtin_amdgcn_s_barrier();                      // all PV done, K landed
    STAGE_V(kt0 + it + 1);                             // overlaps next QK
    cur ^= 1;
  }
  // epilogue tile (no prefetch)
#pragma unroll
  for (int g2 = 0; g2 < 2; ++g2)
#pragma unroll
    for (int g = 0; g < 4; ++g) s[g2][g] = (f32x4){0.f, 0.f, 0.f, 0.f};
  COMPUTE_QK(cur);
  SOFTMAX_P();
  asm volatile("s_waitcnt vmcnt(0)" ::: "memory");
  __builtin_amdgcn_s_barrier();
  COMPUTE_PV();

#undef STAGE_K
#undef STAGE_V
#undef COMPUTE_QK
#undef SOFTMAX_P
#undef COMPUTE_PV

  const int sbase = split * HWPX;
#pragma unroll
  for (int g2 = 0; g2 < 2; ++g2)
#pragma unroll
    for (int dc = 0; dc < 8; ++dc)
#pragma unroll
      for (int r = 0; r < 4; ++r) {
        int q = qb + w * 32 + g2 * 16 + hi * 4 + r;
        Opart[(size_t)(sbase + q) * 128 + dc * 16 + l16] = oacc[g2][dc][r];
      }
  if (l16 == 0) {
#pragma unroll
    for (int g2 = 0; g2 < 2; ++g2)
#pragma unroll
      for (int r = 0; r < 4; ++r) {
        int q = qb + w * 32 + g2 * 16 + hi * 4 + r;
        mOut[sbase + q] = m[g2][r];
        lOut[sbase + q] = l[g2][r];
      }
  }
}

// ---------------------------------------------------------------------------
// combine split-K partials -> att bf16 (px, c).
// ---------------------------------------------------------------------------
__global__ __launch_bounds__(256) void flash_combine(
    const float* __restrict__ Opart, const float* __restrict__ mArr,
    const float* __restrict__ lArr, __bf16* __restrict__ attb, int ksplit) {
  int idx = blockIdx.x * 256 + threadIdx.x;   // q*32 + d4
  int q = idx >> 5, d4 = idx & 31;
  float M = -INFINITY;
  for (int i = 0; i < ksplit; ++i) M = fmaxf(M, mArr[i * HWPX + q]);
  float denom = 0.f;
  f32x4 acc = (f32x4){0.f, 0.f, 0.f, 0.f};
  for (int i = 0; i < ksplit; ++i) {
    float wi = __expf(mArr[i * HWPX + q] - M);
    denom += lArr[i * HWPX + q] * wi;
    f32x4 v = *(const f32x4*)&Opart[((size_t)i * HWPX + q) * 128 + d4 * 4];
#pragma unroll
    for (int e = 0; e < 4; ++e) acc[e] += wi * v[e];
  }
  float inv = 1.f / denom;
  bf16x4 r;
#pragma unroll
  for (int e = 0; e < 4; ++e) r[e] = (__bf16)(acc[e] * inv);
  *(bf16x4*)&attb[(size_t)q * 128 + d4 * 4] = r;
}

// ---------------------------------------------------------------------------
// conv3x3 (SAME) + bias + exact GELU.  att is bf16 (px,c).  32-px tiles.
// ---------------------------------------------------------------------------
__global__ __launch_bounds__(256) void conv3x3_gelu(
    const __bf16* __restrict__ attb, const __bf16* __restrict__ wck,
    const float* __restrict__ bc, const float* __restrict__ resid,
    float* __restrict__ out, __bf16* __restrict__ xbo) {
  __shared__ __align__(16) unsigned char smem[26112];  // 102 px * 256B
  const int tid = threadIdx.x;
  const int y   = blockIdx.x / 3;
  const int x0  = (blockIdx.x % 3) * 32;
  const int lane = tid & 63, w = tid >> 6;
  const int l16 = lane & 15, hi = lane >> 4;

  for (int id = tid; id < 1632; id += 256) {     // 102 px x 16 chunks of 16B
    int px = id >> 4, ch = id & 15;
    int hy = px / 34, hx = px - hy * 34;
    int gy = y + hy - 1, gx = x0 + hx - 1;
    bf16x8 v;
    if (gy >= 0 && gy < 96 && gx >= 0 && gx < 96) {
      v = *(const bf16x8*)&attb[(size_t)(gy * 96 + gx) * 128 + ch * 8];
    } else {
#pragma unroll
      for (int e = 0; e < 8; ++e) v[e] = (__bf16)0.f;
    }
    *(bf16x8*)&smem[px * 256 + ((ch * 16) ^ ((px & 7) << 4))] = v;
  }
  __syncthreads();

  f32x4 acc[2][2];
#pragma unroll
  for (int ot = 0; ot < 2; ++ot) {
    int obase = w * 32 + ot * 16 + hi * 4;
#pragma unroll
    for (int pt = 0; pt < 2; ++pt)
#pragma unroll
      for (int r = 0; r < 4; ++r) acc[ot][pt][r] = bc[obase + r];
  }

  for (int tap = 0; tap < 9; ++tap) {
    int dy = tap / 3, dx = tap - dy * 3;
#pragma unroll
    for (int cc = 0; cc < 4; ++cc) {
      bf16x8 af[2];
#pragma unroll
      for (int ot = 0; ot < 2; ++ot)
        af[ot] = *(const bf16x8*)&wck[(tap * 128 + w * 32 + ot * 16 + l16) * 128 +
                                      cc * 32 + hi * 8];
#pragma unroll
      for (int pt = 0; pt < 2; ++pt) {
        int px = dy * 34 + pt * 16 + l16 + dx;
        bf16x8 bf = *(const bf16x8*)&smem[px * 256 +
                        ((cc * 64 + hi * 16) ^ ((px & 7) << 4))];
#pragma unroll
        for (int ot = 0; ot < 2; ++ot)
          acc[ot][pt] = __builtin_amdgcn_mfma_f32_16x16x32_bf16(af[ot], bf, acc[ot][pt], 0, 0, 0);
      }
    }
  }

  // GELU
  float ge[2][2][4];
#pragma unroll
  for (int ot = 0; ot < 2; ++ot)
#pragma unroll
    for (int pt = 0; pt < 2; ++pt)
#pragma unroll
      for (int r = 0; r < 4; ++r) {
        float v = acc[ot][pt][r];
        ge[ot][pt][r] = 0.5f * v * (1.f + erff(v * 0.70710678118654752f));
      }

  if (xbo) {
    __syncthreads();
#pragma unroll
    for (int ot = 0; ot < 2; ++ot)
#pragma unroll
      for (int pt = 0; pt < 2; ++pt)
#pragma unroll
        for (int r = 0; r < 4; ++r) {
          int o  = w * 32 + ot * 16 + hi * 4 + r;
          int pl = pt * 16 + l16;            // 0..31
          *(__bf16*)&smem[pl * 256 + ((o * 2) ^ ((pl & 7) << 4))] =
              (__bf16)ge[ot][pt][r];
        }
    __syncthreads();
    for (int id = tid; id < 512; id += 256) {  // 32 px x 16 chunks
      int pl = id >> 4, ch = id & 15;
      bf16x8 v = *(const bf16x8*)&smem[pl * 256 + ((ch * 16) ^ ((pl & 7) << 4))];
      *(bf16x8*)&xbo[(size_t)(y * 96 + x0 + pl) * 128 + ch * 8] = v;
    }
  } else {
#pragma unroll
    for (int ot = 0; ot < 2; ++ot)
#pragma unroll
      for (int pt = 0; pt < 2; ++pt)
#pragma unroll
        for (int r = 0; r < 4; ++r) {
          int o  = w * 32 + ot * 16 + hi * 4 + r;
          int px = y * 96 + x0 + pt * 16 + l16;
          out[o * HWPX + px] = ge[ot][pt][r] + resid[o * HWPX + px];
        }
  }
}

// ---------------------------------------------------------------------------
extern "C" void kernel_launch(void* const* d_in, const int* in_sizes, int n_in,
                              void* d_out, int out_size, void* d_ws, size_t ws_size,
                              hipStream_t stream) {
  const float* x  = (const float*)d_in[0];
  const float* w1 = (const float*)d_in[1];
  const float* b1 = (const float*)d_in[2];
  const float* a1 = (const float*)d_in[3];
  const float* w2 = (const float*)d_in[4];
  const float* b2 = (const float*)d_in[5];
  const float* a2 = (const float*)d_in[6];
  const float* w3 = (const float*)d_in[7];
  const float* b3 = (const float*)d_in[8];
  const float* a3 = (const float*)d_in[9];
  const float* wc = (const float*)d_in[10];
  const float* bc = (const float*)d_in[11];
  float* out = (float*)d_out;

  char* ws = (char*)d_ws;
  __bf16* attb = (__bf16*)(ws + 0);          // 2359296
  __bf16* Qb  = (__bf16*)(ws + 2359296);     // 2359296
  __bf16* Kb  = (__bf16*)(ws + 4718592);     // 2359296
  __bf16* Vt  = (__bf16*)(ws + 7077888);     // 2359296
  __bf16* Xb  = (__bf16*)(ws + 9437184);     // 2359296
  __bf16* Wb  = (__bf16*)(ws + 11796480);    // 98304
  __bf16* wck = (__bf16*)(ws + 11894784);    // 294912
  const size_t base_end = 12189696;

  int ksplit = 1;
  if (ws_size >= base_end + 8ull * (4718592 + 2 * 36864)) ksplit = 8;
  else if (ws_size >= base_end + 4ull * (4718592 + 2 * 36864)) ksplit = 4;
  else if (ws_size >= base_end + 2ull * (4718592 + 2 * 36864)) ksplit = 2;
  float* Opart = (float*)(ws + base_end);
  float* mArr  = (float*)(ws + base_end + (size_t)ksplit * 4718592);
  float* lArr  = (float*)(ws + base_end + (size_t)ksplit * (4718592 + 36864));

  prep_kernel<<<576, 256, 0, stream>>>(w1, w2, w3, wc, x, Wb, wck, Xb);

  for (int u = 0; u < 3; ++u) {
    conv1x1_qkv<<<dim3(144, 6), 256, 0, stream>>>(Xb, Wb, b1, b2, b3, a1, a2, a3,
                                                  Qb, Kb, Vt);
    flash_attn<<<dim3(72, ksplit), 256, 0, stream>>>(
        Qb, Kb, Vt, Opart, mArr, lArr, 144 / ksplit);
    flash_combine<<<1152, 256, 0, stream>>>(Opart, mArr, lArr, attb, ksplit);
    conv3x3_gelu<<<288, 256, 0, stream>>>(attb, wck, bc,
                                          (u == 2) ? x : nullptr,
                                          (u == 2) ? out : nullptr,
                                          (u < 2) ? Xb : nullptr);
  }
}

// Round 8
// 440.984 us; speedup vs baseline: 1.3466x; 1.3466x over previous
//
#include <hip/hip_runtime.h>

#define HWPX 9216   // 96*96
#define NCH  128

typedef float  f32x4  __attribute__((ext_vector_type(4)));
typedef __bf16 bf16x8 __attribute__((ext_vector_type(8)));
typedef __bf16 bf16x4 __attribute__((ext_vector_type(4)));

#define SWZ16(row) ((((row) & 7) ^ (((row) >> 3) << 1)) << 4)

// DPP max-reduction over a 16-lane row: xor1, xor2 (quad_perm), ror4, ror8.
#define DPP_MAX(v)                                                             \
  do {                                                                         \
    v = fmaxf(v, __int_as_float(__builtin_amdgcn_update_dpp(                   \
               0, __float_as_int(v), 0xB1, 0xF, 0xF, true)));                  \
    v = fmaxf(v, __int_as_float(__builtin_amdgcn_update_dpp(                   \
               0, __float_as_int(v), 0x4E, 0xF, 0xF, true)));                  \
    v = fmaxf(v, __int_as_float(__builtin_amdgcn_update_dpp(                   \
               0, __float_as_int(v), 0x124, 0xF, 0xF, true)));                 \
    v = fmaxf(v, __int_as_float(__builtin_amdgcn_update_dpp(                   \
               0, __float_as_int(v), 0x128, 0xF, 0xF, true)));                 \
  } while (0)

// ---------------------------------------------------------------------------
// prep: Wb = (j,o,c) bf16; wck = (tap,o,c) bf16; Xb = x^T (px,c) bf16.
// ---------------------------------------------------------------------------
__global__ __launch_bounds__(256) void prep_kernel(
    const float* __restrict__ w1, const float* __restrict__ w2,
    const float* __restrict__ w3, const float* __restrict__ wc,
    const float* __restrict__ x,
    __bf16* __restrict__ Wb, __bf16* __restrict__ wck,
    __bf16* __restrict__ Xb) {
  int tid = blockIdx.x * 256 + threadIdx.x;
  int nt  = gridDim.x * 256;
  for (int idx = tid; idx < 3 * 16384; idx += nt) {
    int j = idx >> 14;
    const float* w = (j == 0) ? w1 : (j == 1 ? w2 : w3);
    Wb[idx] = (__bf16)w[idx & 16383];
  }
  for (int idx = tid; idx < 147456; idx += nt) {   // wc is (O, C, 3, 3)
    int k = idx % 9;
    int rest = idx / 9;            // o*128 + c
    int c = rest & 127, o = rest >> 7;
    wck[(k * 128 + o) * 128 + c] = (__bf16)wc[idx];
  }
  for (int idx = tid; idx < 128 * HWPX; idx += nt) {  // x (c,px) -> Xb (px,c)
    int c = idx / HWPX, p = idx - c * HWPX;
    Xb[p * 128 + c] = (__bf16)x[idx];
  }
}

// ---------------------------------------------------------------------------
// conv1x1 x3 + bias + PReLU as MFMA GEMM.  grid (144, 6).
// Q is pre-scaled by log2(e) so flash softmax runs in exp2 domain.
// ---------------------------------------------------------------------------
__global__ __launch_bounds__(256) void conv1x1_qkv(
    const __bf16* __restrict__ Xb, const __bf16* __restrict__ Wb,
    const float* __restrict__ b1, const float* __restrict__ b2,
    const float* __restrict__ b3, const float* __restrict__ a1,
    const float* __restrict__ a2, const float* __restrict__ a3,
    __bf16* __restrict__ Q, __bf16* __restrict__ K, __bf16* __restrict__ Vt) {
  const int tid = threadIdx.x, lane = tid & 63, w = tid >> 6;
  const int l16 = lane & 15, hi = lane >> 4;
  const int p0 = blockIdx.x * 64;
  const int z  = blockIdx.y;

  bf16x8 af[4][4];
#pragma unroll
  for (int pxt = 0; pxt < 4; ++pxt)
#pragma unroll
    for (int kc = 0; kc < 4; ++kc)
      af[pxt][kc] = *(const bf16x8*)&Xb[(p0 + pxt * 16 + l16) * 128 + kc * 32 + hi * 8];

  const int obase = w * 96 + z * 16;
  const int j = obase >> 7;
  const int oo = (obase & 127) + l16;
  bf16x8 bfg[4];
#pragma unroll
  for (int kc = 0; kc < 4; ++kc)
    bfg[kc] = *(const bf16x8*)&Wb[(obase + l16) * 128 + kc * 32 + hi * 8];
  f32x4 acc[4];
#pragma unroll
  for (int pxt = 0; pxt < 4; ++pxt) acc[pxt] = (f32x4){0.f, 0.f, 0.f, 0.f};
#pragma unroll
  for (int kc = 0; kc < 4; ++kc)
#pragma unroll
    for (int pxt = 0; pxt < 4; ++pxt)
      acc[pxt] = __builtin_amdgcn_mfma_f32_16x16x32_bf16(af[pxt][kc], bfg[kc], acc[pxt], 0, 0, 0);

  const float* bp = (j == 0) ? b1 : (j == 1 ? b2 : b3);
  const float bias = bp[oo];
  const float* ap = (j == 0) ? a1 : (j == 1 ? a2 : a3);
  const float sl = ap[0];
#pragma unroll
  for (int pxt = 0; pxt < 4; ++pxt)
#pragma unroll
    for (int r = 0; r < 4; ++r) {
      float v = acc[pxt][r] + bias;
      v = (v >= 0.f) ? v : sl * v;
      int px = p0 + pxt * 16 + hi * 4 + r;
      if (j == 0)      Q[px * 128 + oo] = (__bf16)(v * 1.44269504088896f);
      else if (j == 1) K[px * 128 + oo] = (__bf16)v;
      else             Vt[oo * HWPX + px] = (__bf16)v;
    }
}

// ---------------------------------------------------------------------------
// Flash attention, split-K, 8 waves (128 q/block, 16 q/wave), double-buffered
// K/V tiles via global_load_lds (pre-swizzled global source, LDS linear).
// Softmax in exp2 domain (Q pre-scaled); denominator l accumulated by 2 extra
// MFMA with a ones B-fragment (rides the matrix pipe, zero VALU).
// XCD-aware remap; DPP max; defer-rescale THR=8 (2-domain).
// LDS 80KB (2 x (K16 + V16) + 8 x P2KB) -> 2 blocks/CU.
// ---------------------------------------------------------------------------
__global__ __launch_bounds__(512) void flash_attn(
    const __bf16* __restrict__ Q, const __bf16* __restrict__ Kb,
    const __bf16* __restrict__ Vt, float* __restrict__ Opart,
    float* __restrict__ mOut, float* __restrict__ lOut, int nt) {
  __shared__ __align__(16) unsigned char smem[81920];
  const int tid  = threadIdx.x;
  const int lane = tid & 63;
  const int w    = tid >> 6;      // 0..7
  const int l16  = lane & 15;
  const int hi   = lane >> 4;
  const int ord  = blockIdx.y * 72 + blockIdx.x;
  const int nsp  = gridDim.y;
  const int split = ord % nsp;
  const int qb   = (ord / nsp) * 128;
  const int kt0  = split * nt;

  // staging: waves 0-3 stage K tile (segs 0..15), waves 4-7 stage V (16..31)
  const __bf16* gsrc[4];
  unsigned loff[4];
  long gstep;
  if (w < 4) {
    gstep = 8192;                              // 64 rows * 128
#pragma unroll
    for (int j = 0; j < 4; ++j) {
      int seg = w * 4 + j;
      int row = seg * 4 + (lane >> 4);
      int ch  = lane & 15;
      gsrc[j] = Kb + (size_t)(kt0 * 64 + row) * 128 + (ch ^ (row & 7)) * 8;
      loff[j] = seg * 1024;
    }
  } else {
    gstep = 64;
#pragma unroll
    for (int j = 0; j < 4; ++j) {
      int seg = (w - 4) * 4 + j;
      int d  = seg * 8 + (lane >> 3);
      int ch = lane & 7;
      gsrc[j] = Vt + (size_t)d * HWPX + kt0 * 64 + (ch ^ (d & 7)) * 8;
      loff[j] = 16384 + seg * 1024;
    }
  }

#define STAGE(BUF) do {                                                        \
  _Pragma("unroll")                                                            \
  for (int j = 0; j < 4; ++j) {                                                \
    __builtin_amdgcn_global_load_lds(                                          \
        (const __attribute__((address_space(1))) unsigned int*)gsrc[j],        \
        (__attribute__((address_space(3))) unsigned int*)(smem + (BUF) * 32768 \
                                                          + loff[j]),          \
        16, 0, 0);                                                             \
    gsrc[j] += gstep;                                                          \
  } } while (0)

  bf16x8 qf[4];
  const int qrow = qb + w * 16 + l16;
#pragma unroll
  for (int dc = 0; dc < 4; ++dc)
    qf[dc] = *(const bf16x8*)&Q[qrow * 128 + dc * 32 + hi * 8];

  bf16x8 ones;
#pragma unroll
  for (int e = 0; e < 8; ++e) ones[e] = (__bf16)1.0f;

  f32x4 oacc[8];
  f32x4 oacc_l = (f32x4){0.f, 0.f, 0.f, 0.f};
#pragma unroll
  for (int dc = 0; dc < 8; ++dc) oacc[dc] = (f32x4){0.f, 0.f, 0.f, 0.f};
  float m[4];
#pragma unroll
  for (int r = 0; r < 4; ++r) m[r] = -INFINITY;

  const unsigned pbase = 65536 + w * 2048;

  STAGE(0);
  __syncthreads();

  int cur = 0;
  for (int it = 0; it < nt; ++it) {
    if (it + 1 < nt) STAGE(cur ^ 1);

    const unsigned kb0 = cur * 32768;
    // S = Q K^T   (16 queries x 64 keys per wave), exp2 domain
    f32x4 s[4];
    __builtin_amdgcn_s_setprio(1);
#pragma unroll
    for (int g = 0; g < 4; ++g) {
      s[g] = (f32x4){0.f, 0.f, 0.f, 0.f};
      int row = g * 16 + l16;
#pragma unroll
      for (int dc = 0; dc < 4; ++dc) {
        bf16x8 kf = *(const bf16x8*)&smem[kb0 + row * 256 +
                        ((dc * 64 + hi * 16) ^ ((row & 7) << 4))];
        s[g] = __builtin_amdgcn_mfma_f32_16x16x32_bf16(qf[dc], kf, s[g], 0, 0, 0);
      }
    }
    __builtin_amdgcn_s_setprio(0);

    // online softmax: DPP max, defer-rescale, exp2
    float mx[4];
#pragma unroll
    for (int r = 0; r < 4; ++r) {
      mx[r] = fmaxf(fmaxf(s[0][r], s[1][r]), fmaxf(s[2][r], s[3][r]));
      DPP_MAX(mx[r]);
    }
    bool need = false;
#pragma unroll
    for (int r = 0; r < 4; ++r) need = need || (mx[r] > m[r] + 8.f);
    if (__any(need)) {
#pragma unroll
      for (int r = 0; r < 4; ++r) {
        float mn = fmaxf(m[r], mx[r]);
        float alpha = __builtin_amdgcn_exp2f(m[r] - mn);
        m[r] = mn;
        oacc_l[r] *= alpha;
#pragma unroll
        for (int dc = 0; dc < 8; ++dc) oacc[dc][r] *= alpha;
      }
    }
#pragma unroll
    for (int g = 0; g < 4; ++g)
#pragma unroll
      for (int r = 0; r < 4; ++r) {
        int row = hi * 4 + r;
        *(__bf16*)&smem[pbase + row * 128 +
                        ((g * 32 + l16 * 2) ^ SWZ16(row))] =
            (__bf16)__builtin_amdgcn_exp2f(s[g][r] - m[r]);
      }
    bf16x8 pa[2];
#pragma unroll
    for (int kc = 0; kc < 2; ++kc)
      pa[kc] = *(const bf16x8*)&smem[pbase + l16 * 128 +
                   ((kc * 64 + hi * 16) ^ SWZ16(l16))];
    __builtin_amdgcn_s_setprio(1);
#pragma unroll
    for (int dc = 0; dc < 8; ++dc) {
#pragma unroll
      for (int kc = 0; kc < 2; ++kc) {
        int row = dc * 16 + l16;
        bf16x8 vf = *(const bf16x8*)&smem[kb0 + 16384 + row * 128 +
                        ((kc * 64 + hi * 16) ^ ((row & 7) << 4))];
        oacc[dc] = __builtin_amdgcn_mfma_f32_16x16x32_bf16(pa[kc], vf, oacc[dc], 0, 0, 0);
      }
    }
    // denominator: l += P . ones  (matrix pipe, no VALU)
    oacc_l = __builtin_amdgcn_mfma_f32_16x16x32_bf16(pa[0], ones, oacc_l, 0, 0, 0);
    oacc_l = __builtin_amdgcn_mfma_f32_16x16x32_bf16(pa[1], ones, oacc_l, 0, 0, 0);
    __builtin_amdgcn_s_setprio(0);
    __syncthreads();
    cur ^= 1;
  }
#undef STAGE

  const int sbase = split * HWPX;
#pragma unroll
  for (int dc = 0; dc < 8; ++dc)
#pragma unroll
    for (int r = 0; r < 4; ++r) {
      int q = qb + w * 16 + hi * 4 + r;
      Opart[(size_t)(sbase + q) * 128 + dc * 16 + l16] = oacc[dc][r];
    }
  if (l16 == 0) {
#pragma unroll
    for (int r = 0; r < 4; ++r) {
      int q = qb + w * 16 + hi * 4 + r;
      mOut[sbase + q] = m[r];
      lOut[sbase + q] = oacc_l[r];
    }
  }
}

// ---------------------------------------------------------------------------
// combine split-K partials -> att bf16 (px, c).  exp2 domain.
// ---------------------------------------------------------------------------
__global__ __launch_bounds__(256) void flash_combine(
    const float* __restrict__ Opart, const float* __restrict__ mArr,
    const float* __restrict__ lArr, __bf16* __restrict__ attb, int ksplit) {
  int idx = blockIdx.x * 256 + threadIdx.x;   // q*32 + d4
  int q = idx >> 5, d4 = idx & 31;
  float M = -INFINITY;
  for (int i = 0; i < ksplit; ++i) M = fmaxf(M, mArr[i * HWPX + q]);
  float denom = 0.f;
  f32x4 acc = (f32x4){0.f, 0.f, 0.f, 0.f};
  for (int i = 0; i < ksplit; ++i) {
    float wi = __builtin_amdgcn_exp2f(mArr[i * HWPX + q] - M);
    denom += lArr[i * HWPX + q] * wi;
    f32x4 v = *(const f32x4*)&Opart[((size_t)i * HWPX + q) * 128 + d4 * 4];
#pragma unroll
    for (int e = 0; e < 4; ++e) acc[e] += wi * v[e];
  }
  float inv = 1.f / denom;
  bf16x4 r;
#pragma unroll
  for (int e = 0; e < 4; ++e) r[e] = (__bf16)(acc[e] * inv);
  *(bf16x4*)&attb[(size_t)q * 128 + d4 * 4] = r;
}

// ---------------------------------------------------------------------------
// conv3x3 (SAME) + bias + exact GELU.  att bf16 (px,c).  32-px x 64-o tiles,
// grid (288, 2) = 576 blocks (o split halves MFMA/block, doubles width).
// ---------------------------------------------------------------------------
__global__ __launch_bounds__(256) void conv3x3_gelu(
    const __bf16* __restrict__ attb, const __bf16* __restrict__ wck,
    const float* __restrict__ bc, const float* __restrict__ resid,
    float* __restrict__ out, __bf16* __restrict__ xbo) {
  __shared__ __align__(16) unsigned char smem[26112];  // 102 px * 256B
  const int tid = threadIdx.x;
  const int y   = blockIdx.x / 3;
  const int x0  = (blockIdx.x % 3) * 32;
  const int oh  = blockIdx.y;              // o half: 0 or 1
  const int lane = tid & 63, w = tid >> 6;
  const int l16 = lane & 15, hi = lane >> 4;

  for (int id = tid; id < 1632; id += 256) {     // 102 px x 16 chunks of 16B
    int px = id >> 4, ch = id & 15;
    int hy = px / 34, hx = px - hy * 34;
    int gy = y + hy - 1, gx = x0 + hx - 1;
    bf16x8 v;
    if (gy >= 0 && gy < 96 && gx >= 0 && gx < 96) {
      v = *(const bf16x8*)&attb[(size_t)(gy * 96 + gx) * 128 + ch * 8];
    } else {
#pragma unroll
      for (int e = 0; e < 8; ++e) v[e] = (__bf16)0.f;
    }
    *(bf16x8*)&smem[px * 256 + ((ch * 16) ^ ((px & 7) << 4))] = v;
  }
  __syncthreads();

  const int ob = oh * 64 + w * 16;         // this wave's 16-o block
  f32x4 acc[2];
#pragma unroll
  for (int pt = 0; pt < 2; ++pt)
#pragma unroll
    for (int r = 0; r < 4; ++r) acc[pt][r] = bc[ob + hi * 4 + r];

  for (int tap = 0; tap < 9; ++tap) {
    int dy = tap / 3, dx = tap - dy * 3;
#pragma unroll
    for (int cc = 0; cc < 4; ++cc) {
      bf16x8 af = *(const bf16x8*)&wck[(tap * 128 + ob + l16) * 128 +
                                       cc * 32 + hi * 8];
#pragma unroll
      for (int pt = 0; pt < 2; ++pt) {
        int px = dy * 34 + pt * 16 + l16 + dx;
        bf16x8 bf = *(const bf16x8*)&smem[px * 256 +
                        ((cc * 64 + hi * 16) ^ ((px & 7) << 4))];
        acc[pt] = __builtin_amdgcn_mfma_f32_16x16x32_bf16(af, bf, acc[pt], 0, 0, 0);
      }
    }
  }

  // GELU
  float ge[2][4];
#pragma unroll
  for (int pt = 0; pt < 2; ++pt)
#pragma unroll
    for (int r = 0; r < 4; ++r) {
      float v = acc[pt][r];
      ge[pt][r] = 0.5f * v * (1.f + erff(v * 0.70710678118654752f));
    }

  if (xbo) {
    // transpose via LDS: rows = 32 px, 128B of this o-half's 64 channels
    __syncthreads();
#pragma unroll
    for (int pt = 0; pt < 2; ++pt)
#pragma unroll
      for (int r = 0; r < 4; ++r) {
        int oc = w * 16 + hi * 4 + r;      // 0..63 within half
        int pl = pt * 16 + l16;            // 0..31
        *(__bf16*)&smem[pl * 256 + ((oc * 2) ^ ((pl & 7) << 4))] =
            (__bf16)ge[pt][r];
      }
    __syncthreads();
    for (int id = tid; id < 256; id += 256) {  // 32 px x 8 chunks of 16B
      int pl = id >> 3, ch = id & 7;
      bf16x8 v = *(const bf16x8*)&smem[pl * 256 + ((ch * 16) ^ ((pl & 7) << 4))];
      *(bf16x8*)&xbo[(size_t)(y * 96 + x0 + pl) * 128 + oh * 64 + ch * 8] = v;
    }
  } else {
#pragma unroll
    for (int pt = 0; pt < 2; ++pt)
#pragma unroll
      for (int r = 0; r < 4; ++r) {
        int o  = ob + hi * 4 + r;
        int px = y * 96 + x0 + pt * 16 + l16;
        out[o * HWPX + px] = ge[pt][r] + resid[o * HWPX + px];
      }
  }
}

// ---------------------------------------------------------------------------
extern "C" void kernel_launch(void* const* d_in, const int* in_sizes, int n_in,
                              void* d_out, int out_size, void* d_ws, size_t ws_size,
                              hipStream_t stream) {
  const float* x  = (const float*)d_in[0];
  const float* w1 = (const float*)d_in[1];
  const float* b1 = (const float*)d_in[2];
  const float* a1 = (const float*)d_in[3];
  const float* w2 = (const float*)d_in[4];
  const float* b2 = (const float*)d_in[5];
  const float* a2 = (const float*)d_in[6];
  const float* w3 = (const float*)d_in[7];
  const float* b3 = (const float*)d_in[8];
  const float* a3 = (const float*)d_in[9];
  const float* wc = (const float*)d_in[10];
  const float* bc = (const float*)d_in[11];
  float* out = (float*)d_out;

  char* ws = (char*)d_ws;
  __bf16* attb = (__bf16*)(ws + 0);          // 2359296
  __bf16* Qb  = (__bf16*)(ws + 2359296);     // 2359296
  __bf16* Kb  = (__bf16*)(ws + 4718592);     // 2359296
  __bf16* Vt  = (__bf16*)(ws + 7077888);     // 2359296
  __bf16* Xb  = (__bf16*)(ws + 9437184);     // 2359296
  __bf16* Wb  = (__bf16*)(ws + 11796480);    // 98304
  __bf16* wck = (__bf16*)(ws + 11894784);    // 294912
  const size_t base_end = 12189696;

  int ksplit = 1;
  if (ws_size >= base_end + 8ull * (4718592 + 2 * 36864)) ksplit = 8;
  else if (ws_size >= base_end + 4ull * (4718592 + 2 * 36864)) ksplit = 4;
  else if (ws_size >= base_end + 2ull * (4718592 + 2 * 36864)) ksplit = 2;
  float* Opart = (float*)(ws + base_end);
  float* mArr  = (float*)(ws + base_end + (size_t)ksplit * 4718592);
  float* lArr  = (float*)(ws + base_end + (size_t)ksplit * (4718592 + 36864));

  prep_kernel<<<576, 256, 0, stream>>>(w1, w2, w3, wc, x, Wb, wck, Xb);

  for (int u = 0; u < 3; ++u) {
    conv1x1_qkv<<<dim3(144, 6), 256, 0, stream>>>(Xb, Wb, b1, b2, b3, a1, a2, a3,
                                                  Qb, Kb, Vt);
    flash_attn<<<dim3(72, ksplit), 512, 0, stream>>>(
        Qb, Kb, Vt, Opart, mArr, lArr, 144 / ksplit);
    flash_combine<<<1152, 256, 0, stream>>>(Opart, mArr, lArr, attb, ksplit);
    conv3x3_gelu<<<dim3(288, 2), 256, 0, stream>>>(attb, wck, bc,
                                                   (u == 2) ? x : nullptr,
                                                   (u == 2) ? out : nullptr,
                                                   (u < 2) ? Xb : nullptr);
  }
}